// Round 1
// baseline (1328.866 us; speedup 1.0000x reference)
//
#include <hip/hip_runtime.h>

// Problem constants (match reference)
constexpr int NN = 100000;   // nodes
constexpr int NE = 1250000;  // edges
constexpr int D  = 64;       // in == out dim
constexpr int NB = 16;       // bases

// ---------------------------------------------------------------------------
// Kernel 1: collapse bases -> W_msg[4096], W_self[4096], b_msg[64], b_self[64]
// W layout: W[i*64 + o]  (row = input dim i, col = output dim o)
// ---------------------------------------------------------------------------
__global__ void combine_kernel(const float* __restrict__ wm,
                               const float* __restrict__ bm,
                               const float* __restrict__ wsf,
                               const float* __restrict__ bsf,
                               const float* __restrict__ lc,
                               float* __restrict__ W,   // [8192]: W_msg | W_self
                               float* __restrict__ B)   // [128]:  b_msg | b_self
{
    __shared__ float c[NB];
    if (threadIdx.x < NB) c[threadIdx.x] = lc[threadIdx.x];
    __syncthreads();

    int t = blockIdx.x * blockDim.x + threadIdx.x;
    if (t < 4096) {
        const float* p = wm + t * NB;
        float s = 0.f;
        #pragma unroll
        for (int b = 0; b < NB; ++b) s += p[b] * c[b];
        W[t] = s;
    } else if (t < 8192) {
        const float* p = wsf + (t - 4096) * NB;
        float s = 0.f;
        #pragma unroll
        for (int b = 0; b < NB; ++b) s += p[b] * c[b];
        W[t] = s;
    } else if (t < 8192 + 64) {
        const float* p = bm + (t - 8192) * NB;
        float s = 0.f;
        #pragma unroll
        for (int b = 0; b < NB; ++b) s += p[b] * c[b];
        B[t - 8192] = s;
    } else if (t < 8192 + 128) {
        const float* p = bsf + (t - 8192 - 64) * NB;
        float s = 0.f;
        #pragma unroll
        for (int b = 0; b < NB; ++b) s += p[b] * c[b];
        B[t - 8192 - 64 + 64] = s;
    }
}

// ---------------------------------------------------------------------------
// Kernel 2: zero the aggregation buffer (d_out doubles as agg) and deg[]
// ---------------------------------------------------------------------------
__global__ void zero_kernel(float4* __restrict__ agg4, float* __restrict__ deg)
{
    int stride = gridDim.x * blockDim.x;
    int i = blockIdx.x * blockDim.x + threadIdx.x;
    const int total4 = NN * D / 4;
    for (int j = i; j < total4; j += stride)
        agg4[j] = make_float4(0.f, 0.f, 0.f, 0.f);
    for (int j = i; j < NN; j += stride)
        deg[j] = 0.f;
}

// ---------------------------------------------------------------------------
// Kernel 3: scatter-add raw features. 16 lanes per edge, float4 each.
// agg[dst] += x[src]; deg[dst] += 1
// ---------------------------------------------------------------------------
__global__ __launch_bounds__(256)
void scatter_kernel(const float* __restrict__ x,
                    const int* __restrict__ ei,
                    float* __restrict__ agg,
                    float* __restrict__ deg)
{
    int gt = blockIdx.x * blockDim.x + threadIdx.x;
    int e = gt >> 4;
    if (e >= NE) return;
    int sub = gt & 15;

    int src = ei[e];
    int dst = ei[NE + e];

    float4 v = *reinterpret_cast<const float4*>(x + (size_t)src * D + sub * 4);
    float* a = agg + (size_t)dst * D + sub * 4;
    atomicAdd(a + 0, v.x);
    atomicAdd(a + 1, v.y);
    atomicAdd(a + 2, v.z);
    atomicAdd(a + 3, v.w);
    if (sub == 0) atomicAdd(deg + dst, 1.0f);
}

// ---------------------------------------------------------------------------
// Kernel 4: per node:  out = normalize(agg @ W_msg + deg*b_msg + x @ W_self + b_self)
// One wave (64 lanes) per node; lane = output dim o. Weights staged in LDS.
// In-place: agg rows live in d_out; each wave reads its row fully before writing.
// ---------------------------------------------------------------------------
constexpr int NODES_PER_BLOCK = 16;

__global__ __launch_bounds__(256)
void output_kernel(const float* __restrict__ x,
                   float* __restrict__ out,          // agg in, result out
                   const float* __restrict__ deg,
                   const float* __restrict__ W,      // [8192]
                   const float* __restrict__ B)      // [128]
{
    __shared__ float sW[2 * 4096];
    __shared__ float sB[128];

    for (int i = threadIdx.x; i < 8192; i += 256) sW[i] = W[i];
    if (threadIdx.x < 128) sB[threadIdx.x] = B[threadIdx.x];
    __syncthreads();

    const int wave = threadIdx.x >> 6;
    const int lane = threadIdx.x & 63;
    const int base = blockIdx.x * NODES_PER_BLOCK;

    for (int k = wave; k < NODES_PER_BLOCK; k += 4) {
        int n = base + k;
        if (n >= NN) break;

        float xv = x[(size_t)n * D + lane];
        float av = out[(size_t)n * D + lane];   // agg row (read before write)
        float dg = deg[n];

        float acc = dg * sB[lane] + sB[64 + lane];
        #pragma unroll 8
        for (int i = 0; i < D; ++i) {
            float ai = __shfl(av, i, 64);
            float xi = __shfl(xv, i, 64);
            acc += ai * sW[i * D + lane] + xi * sW[4096 + i * D + lane];
        }

        // L2 norm across the 64 lanes
        float s = acc * acc;
        #pragma unroll
        for (int off = 32; off; off >>= 1) s += __shfl_xor(s, off, 64);
        float norm = sqrtf(s);

        out[(size_t)n * D + lane] = acc / fmaxf(norm, 1e-12f);
    }
}

// ---------------------------------------------------------------------------
extern "C" void kernel_launch(void* const* d_in, const int* in_sizes, int n_in,
                              void* d_out, int out_size, void* d_ws, size_t ws_size,
                              hipStream_t stream)
{
    const float* x   = (const float*)d_in[0];
    const int*   ei  = (const int*)d_in[1];
    const float* wm  = (const float*)d_in[2];
    const float* bm  = (const float*)d_in[3];
    const float* wsf = (const float*)d_in[4];
    const float* bsf = (const float*)d_in[5];
    const float* lc  = (const float*)d_in[6];

    float* out = (float*)d_out;

    // workspace layout: W[8192] | B[128] | deg[NN]
    float* W   = (float*)d_ws;
    float* Bv  = W + 8192;
    float* deg = Bv + 128;

    // 1. combine bases
    combine_kernel<<<(8192 + 128 + 255) / 256, 256, 0, stream>>>(wm, bm, wsf, bsf, lc, W, Bv);

    // 2. zero agg (= d_out) and deg
    zero_kernel<<<2048, 256, 0, stream>>>((float4*)out, deg);

    // 3. scatter raw features
    {
        long long threads = (long long)NE * 16;
        int blocks = (int)((threads + 255) / 256);
        scatter_kernel<<<blocks, 256, 0, stream>>>(x, ei, out, deg);
    }

    // 4. transform + normalize (in place over d_out)
    output_kernel<<<(NN + NODES_PER_BLOCK - 1) / NODES_PER_BLOCK, 256, 0, stream>>>(
        x, out, deg, W, Bv);
}

// Round 2
// 390.517 us; speedup vs baseline: 3.4028x; 3.4028x over previous
//
#include <hip/hip_runtime.h>

// Problem constants (match reference)
constexpr int NN = 100000;   // nodes
constexpr int NE = 1250000;  // edges
constexpr int D  = 64;       // in == out dim
constexpr int NB = 16;       // bases
constexpr int NBLK = (NN + 255) / 256;   // 391 scan blocks

// ---------------------------------------------------------------------------
// Kernel 1: collapse bases -> W_msg[4096], W_self[4096], b_msg[64], b_self[64]
// W layout: W[i*64 + o]
// ---------------------------------------------------------------------------
__global__ void combine_kernel(const float* __restrict__ wm,
                               const float* __restrict__ bm,
                               const float* __restrict__ wsf,
                               const float* __restrict__ bsf,
                               const float* __restrict__ lc,
                               float* __restrict__ W,   // [8192]: W_msg | W_self
                               float* __restrict__ B)   // [128]:  b_msg | b_self
{
    __shared__ float c[NB];
    if (threadIdx.x < NB) c[threadIdx.x] = lc[threadIdx.x];
    __syncthreads();

    int t = blockIdx.x * blockDim.x + threadIdx.x;
    if (t < 4096) {
        const float* p = wm + t * NB;
        float s = 0.f;
        #pragma unroll
        for (int b = 0; b < NB; ++b) s += p[b] * c[b];
        W[t] = s;
    } else if (t < 8192) {
        const float* p = wsf + (t - 4096) * NB;
        float s = 0.f;
        #pragma unroll
        for (int b = 0; b < NB; ++b) s += p[b] * c[b];
        W[t] = s;
    } else if (t < 8192 + 64) {
        const float* p = bm + (t - 8192) * NB;
        float s = 0.f;
        #pragma unroll
        for (int b = 0; b < NB; ++b) s += p[b] * c[b];
        B[t - 8192] = s;
    } else if (t < 8192 + 128) {
        const float* p = bsf + (t - 8192 - 64) * NB;
        float s = 0.f;
        #pragma unroll
        for (int b = 0; b < NB; ++b) s += p[b] * c[b];
        B[t - 8192 - 64 + 64] = s;
    }
}

// ---------------------------------------------------------------------------
// Kernel 2: zero the per-node edge counters
// ---------------------------------------------------------------------------
__global__ void zero_counts(int* __restrict__ counts)
{
    int stride = gridDim.x * blockDim.x;
    for (int i = blockIdx.x * blockDim.x + threadIdx.x; i < NN; i += stride)
        counts[i] = 0;
}

// ---------------------------------------------------------------------------
// Kernel 3: histogram of destination nodes
// ---------------------------------------------------------------------------
__global__ void hist_kernel(const int* __restrict__ ei, int* __restrict__ counts)
{
    int e = blockIdx.x * blockDim.x + threadIdx.x;
    if (e < NE) atomicAdd(&counts[ei[NE + e]], 1);
}

// ---------------------------------------------------------------------------
// Kernels 4a/4b/4c: exclusive prefix sum of counts -> offs (start offsets)
// ---------------------------------------------------------------------------
__global__ void scan_block(const int* __restrict__ counts,
                           int* __restrict__ offs,
                           int* __restrict__ partials)
{
    __shared__ int tmp[256];
    int tid = threadIdx.x;
    int i = blockIdx.x * 256 + tid;
    int c = (i < NN) ? counts[i] : 0;
    int v = c;
    tmp[tid] = v;
    __syncthreads();
    for (int off = 1; off < 256; off <<= 1) {
        int t = (tid >= off) ? tmp[tid - off] : 0;
        __syncthreads();
        v += t;
        tmp[tid] = v;
        __syncthreads();
    }
    if (i < NN) offs[i] = v - c;              // exclusive within block
    if (tid == 255) partials[blockIdx.x] = v; // block total
}

__global__ void scan_partials(int* __restrict__ partials)
{
    __shared__ int tmp[512];
    int tid = threadIdx.x;
    int c = (tid < NBLK) ? partials[tid] : 0;
    int v = c;
    tmp[tid] = v;
    __syncthreads();
    for (int off = 1; off < 512; off <<= 1) {
        int t = (tid >= off) ? tmp[tid - off] : 0;
        __syncthreads();
        v += t;
        tmp[tid] = v;
        __syncthreads();
    }
    if (tid < NBLK) partials[tid] = v - c;    // exclusive block offsets
}

__global__ void add_offsets(int* __restrict__ offs, const int* __restrict__ partials)
{
    int i = blockIdx.x * 256 + threadIdx.x;
    if (i < NN) offs[i] += partials[blockIdx.x];
}

// ---------------------------------------------------------------------------
// Kernel 5: bucket-scatter src ids into CSR order.
// NOTE: destroys offs -> afterwards offs[n] == end offset of node n.
// ---------------------------------------------------------------------------
__global__ void scatter_sort(const int* __restrict__ ei,
                             int* __restrict__ offs,
                             int* __restrict__ sorted_src)
{
    int e = blockIdx.x * blockDim.x + threadIdx.x;
    if (e >= NE) return;
    int src = ei[e];
    int dst = ei[NE + e];
    int pos = atomicAdd(&offs[dst], 1);
    sorted_src[pos] = src;
}

// ---------------------------------------------------------------------------
// Kernel 6: fused gather + transform + normalize. One wave per node, lane = dim.
// out = normalize( agg @ W_msg + deg*b_msg + x @ W_self + b_self )
// ---------------------------------------------------------------------------
__global__ __launch_bounds__(256)
void gather_out(const float* __restrict__ x,
                const int* __restrict__ sorted_src,
                const int* __restrict__ offs,     // end offsets
                const int* __restrict__ counts,
                const float* __restrict__ W,      // [8192]
                const float* __restrict__ B,      // [128]
                float* __restrict__ out)
{
    __shared__ float sW[2 * 4096];
    __shared__ float sB[128];
    for (int i = threadIdx.x; i < 8192; i += 256) sW[i] = W[i];
    if (threadIdx.x < 128) sB[threadIdx.x] = B[threadIdx.x];
    __syncthreads();

    const int wave = threadIdx.x >> 6;
    const int lane = threadIdx.x & 63;
    const int n = blockIdx.x * 4 + wave;   // 25000 * 4 == NN exactly
    if (n >= NN) return;

    const int deg = counts[n];
    const int end = offs[n];
    int j = end - deg;

    // gather-sum x[src] rows; 4 independent accumulators for MLP
    float a0 = 0.f, a1 = 0.f, a2 = 0.f, a3 = 0.f;
    for (; j + 4 <= end; j += 4) {
        int s0 = sorted_src[j + 0];
        int s1 = sorted_src[j + 1];
        int s2 = sorted_src[j + 2];
        int s3 = sorted_src[j + 3];
        a0 += x[(size_t)s0 * D + lane];
        a1 += x[(size_t)s1 * D + lane];
        a2 += x[(size_t)s2 * D + lane];
        a3 += x[(size_t)s3 * D + lane];
    }
    for (; j < end; ++j) a0 += x[(size_t)sorted_src[j] * D + lane];
    float av = (a0 + a1) + (a2 + a3);      // agg[lane]

    float xv = x[(size_t)n * D + lane];

    float acc = (float)deg * sB[lane] + sB[64 + lane];
    #pragma unroll 8
    for (int i = 0; i < D; ++i) {
        float ai = __shfl(av, i, 64);
        float xi = __shfl(xv, i, 64);
        acc += ai * sW[i * D + lane] + xi * sW[4096 + i * D + lane];
    }

    // L2 norm across 64 lanes
    float s = acc * acc;
    #pragma unroll
    for (int off = 32; off; off >>= 1) s += __shfl_xor(s, off, 64);
    float norm = sqrtf(s);

    out[(size_t)n * D + lane] = acc / fmaxf(norm, 1e-12f);
}

// ---------------------------------------------------------------------------
extern "C" void kernel_launch(void* const* d_in, const int* in_sizes, int n_in,
                              void* d_out, int out_size, void* d_ws, size_t ws_size,
                              hipStream_t stream)
{
    const float* x   = (const float*)d_in[0];
    const int*   ei  = (const int*)d_in[1];
    const float* wm  = (const float*)d_in[2];
    const float* bm  = (const float*)d_in[3];
    const float* wsf = (const float*)d_in[4];
    const float* bsf = (const float*)d_in[5];
    const float* lc  = (const float*)d_in[6];

    float* out = (float*)d_out;

    // workspace layout (floats/ints, 4B each):
    // W[8192] | B[128] | counts[NN] | offs[NN] | partials[512] | sorted_src[NE]
    float* W        = (float*)d_ws;
    float* Bv       = W + 8192;
    int*   counts   = (int*)(Bv + 128);
    int*   offs     = counts + NN;
    int*   partials = offs + NN;
    int*   sorted_src = partials + 512;

    // 1. combine bases
    combine_kernel<<<(8192 + 128 + 255) / 256, 256, 0, stream>>>(wm, bm, wsf, bsf, lc, W, Bv);

    // 2. zero counters
    zero_counts<<<128, 256, 0, stream>>>(counts);

    // 3. histogram of dst
    hist_kernel<<<(NE + 255) / 256, 256, 0, stream>>>(ei, counts);

    // 4. exclusive scan -> offs
    scan_block<<<NBLK, 256, 0, stream>>>(counts, offs, partials);
    scan_partials<<<1, 512, 0, stream>>>(partials);
    add_offsets<<<NBLK, 256, 0, stream>>>(offs, partials);

    // 5. bucket-scatter src ids (offs becomes end offsets)
    scatter_sort<<<(NE + 255) / 256, 256, 0, stream>>>(ei, offs, sorted_src);

    // 6. fused gather + transform + normalize
    gather_out<<<NN / 4, 256, 0, stream>>>(x, sorted_src, offs, counts, W, Bv, out);
}